// Round 10
// baseline (157.148 us; speedup 1.0000x reference)
//
#include <hip/hip_runtime.h>
#include <hip/hip_bf16.h>
#include <math.h>

// ArcFace loss, MI355X. B=2048, D=512, C=32768.
// R10: R9 fp8 ping-pong GEMM split into 256-thread / 128x128-tile blocks
// (grid 4096). R9 analysis: 61.6us == MFMA floor 33.4 + LDS-read floor 20.5
// + epilogue, i.e. the two pipes fully SERIALIZE because all 8 waves sit in
// one barrier group (phase-locked: read-phase then MFMA-phase). 4 resident
// 256-thr blocks/CU = 4 independent barrier groups in random phase -> block
// i's MFMA overlaps block j's ds_reads (m114 pipe co-scheduling).
// LDS 32.5KB/block, 60+64 regs -> exactly 4 blocks/CU at launch_bounds(256,4).
// Layouts identical to R8/R9 (absmax 0.0, conflicts 0, FETCH ~12MB).

#define BN 2048
#define DK 512
#define CN 32768

typedef __attribute__((ext_vector_type(4))) float floatx4;
typedef __attribute__((ext_vector_type(2))) long longx2;

__device__ inline float dot4(floatx4 a, floatx4 b) {
  return a.x * b.x + a.y * b.y + a.z * b.z + a.w * b.w;
}

__device__ inline int pack_fp8x4(floatx4 v) {
  int r = __builtin_amdgcn_cvt_pk_fp8_f32(v.x, v.y, 0, false);
  r = __builtin_amdgcn_cvt_pk_fp8_f32(v.z, v.w, r, true);
  return r;
}

// dword j (0..15) of a 64B slab -> MFMA-ready position:
// q=(j>>1)&3 (8B piece), p=j>>3 (k-step), dest = q*4 + p*2 + (j&1)
__device__ inline int permute16(int j) {
  return ((j >> 1) & 3) * 4 + (j >> 3) * 2 + (j & 1);
}

__device__ inline void async_ld16(const void* g, void* l) {
  __builtin_amdgcn_global_load_lds(
      (const __attribute__((address_space(1))) void*)g,
      (__attribute__((address_space(3))) void*)l, 16, 0, 0);
}

// ---- kernel 1: fused prep -> fp8 rows (512 B each), MFMA-ready byte order.
__global__ void prep_kernel(const float* __restrict__ feat,
                            const int* __restrict__ y,
                            const float* __restrict__ w,
                            int* __restrict__ fb8,     // [BN][128] dwords
                            int* __restrict__ wb8,     // [CN][128] dwords
                            float* __restrict__ tgt,
                            float* __restrict__ rowsum) {
  const int wave = threadIdx.x >> 6;
  const int l = threadIdx.x & 63;
  const int d0 = ((l >> 4) * 16)       + permute16(l & 15);
  const int d1 = ((4 + (l >> 4)) * 16) + permute16(l & 15);
  if (blockIdx.x < 8192) {
    const int row = blockIdx.x * 4 + wave;
    const floatx4* src = (const floatx4*)(w + (size_t)row * DK);
    floatx4 v0 = src[l];
    floatx4 v1 = src[64 + l];
    float s = dot4(v0, v0) + dot4(v1, v1);
#pragma unroll
    for (int off = 1; off < 64; off <<= 1) s += __shfl_xor(s, off, 64);
    const float scale = 1.0f / fmaxf(sqrtf(s), 1e-12f);
    v0 *= scale; v1 *= scale;
    int* db = wb8 + (size_t)row * 128;
    db[d0] = pack_fp8x4(v0);
    db[d1] = pack_fp8x4(v1);
  } else {
    const int i = (blockIdx.x - 8192) * 4 + wave;
    const floatx4* src = (const floatx4*)(feat + (size_t)i * DK);
    floatx4 v0 = src[l];
    floatx4 v1 = src[64 + l];
    const int cls = y[i];
    const floatx4* wr = (const floatx4*)(w + (size_t)cls * DK);
    floatx4 w0 = wr[l], w1 = wr[64 + l];
    float s  = dot4(v0, v0) + dot4(v1, v1);
    float d  = dot4(v0, w0) + dot4(v1, w1);
    float wn = dot4(w0, w0) + dot4(w1, w1);
#pragma unroll
    for (int off = 1; off < 64; off <<= 1) {
      s  += __shfl_xor(s, off, 64);
      d  += __shfl_xor(d, off, 64);
      wn += __shfl_xor(wn, off, 64);
    }
    const float fscale = 1.0f / fmaxf(sqrtf(s), 1e-12f);
    v0 *= fscale; v1 *= fscale;
    int* db = fb8 + (size_t)i * 128;
    db[d0] = pack_fp8x4(v0);
    db[d1] = pack_fp8x4(v1);
    if (l == 0) {
      tgt[i] = d * fscale / fmaxf(sqrtf(wn), 1e-12f);
      rowsum[i] = 0.0f;
    }
  }
}

// ---- kernel 2: 128x128 fp8 MFMA GEMM (16x16x32), ping-pong LDS,
// one barrier per K-64 slab, fused exp row-sum. 256 thr / 4 waves.
__launch_bounds__(256, 4)
__global__ void gemm_exp_kernel(const char* __restrict__ fb8,   // [BN][512] B
                                const char* __restrict__ wb8,   // [CN][512] B
                                float* __restrict__ rowsum) {
  __shared__ char As[2][128 * 64];   // 2 x 8 KB
  __shared__ char Bs[2][128 * 64];   // 2 x 8 KB
  __shared__ float lsum[128];

  const int tid  = threadIdx.x;
  const int wave = tid >> 6;
  const int lane = tid & 63;

  // XCD swizzle: 4096 blocks = 32 M-tiles x 128 N-tiles; XCD(n%8) owns y%8,
  // sweeping all 32 M-tiles for one N-tile before the next.
  const int n = blockIdx.x;
  const int tileM = ((n >> 3) & 31) * 128;
  const int tileN = (((n >> 8) << 3) | (n & 7)) * 128;

  const int wm = (wave >> 1) * 64;  // wave M offset (0 or 64)
  const int wn = (wave & 1) * 64;   // wave N offset (0 or 64)

  if (tid < 128) lsum[tid] = 0.0f;  // covered by first K-loop barrier

  floatx4 acc[4][4];
#pragma unroll
  for (int mi = 0; mi < 4; ++mi)
#pragma unroll
    for (int ni = 0; ni < 4; ++ni)
      acc[mi][ni] = (floatx4){0.f, 0.f, 0.f, 0.f};

  // staging: per slab A 512 + B 512 16B-units, 4 insts/thread (2 A + 2 B).
  // unit c: row c>>2, stored pos c&3; fetch global unit (c&3)^((row>>1)&3).
  // Second inst covers row+64: ((row+64)>>1)&3 == (row>>1)&3, same unit.
  const int mA = tid >> 2;                    // rows 0..63 (inst0), +64 (inst1)
  const int uA = (tid & 3) ^ ((mA >> 1) & 3);
  const char* gA0 = fb8 + (size_t)(tileM + mA)      * DK + uA * 16;
  const char* gA1 = fb8 + (size_t)(tileM + 64 + mA) * DK + uA * 16;
  const char* gB0 = wb8 + (size_t)(tileN + mA)      * DK + uA * 16;
  const char* gB1 = wb8 + (size_t)(tileN + 64 + mA) * DK + uA * 16;
  const int lds0 = wave * 1024;          // wave-uniform LDS offsets
  const int lds1 = 4096 + wave * 1024;

  // hoisted fragment LDS byte-offsets (loop-invariant)
  const int mrow = lane & 15;
  const int q    = lane >> 4;
  int offA[4], offB[4];
#pragma unroll
  for (int mi = 0; mi < 4; ++mi) {
    const int row = wm + mi * 16 + mrow;
    offA[mi] = row * 64 + (q ^ ((row >> 1) & 3)) * 16;
  }
#pragma unroll
  for (int ni = 0; ni < 4; ++ni) {
    const int row = wn + ni * 16 + mrow;
    offB[ni] = row * 64 + (q ^ ((row >> 1) & 3)) * 16;
  }

  // prologue: stage slab 0 into buffer 0
  async_ld16(gA0, &As[0][lds0]);
  async_ld16(gA1, &As[0][lds1]);
  async_ld16(gB0, &Bs[0][lds0]);
  async_ld16(gB1, &Bs[0][lds1]);
  gA0 += 64; gA1 += 64; gB0 += 64; gB1 += 64;

#pragma unroll
  for (int kk = 0; kk < DK / 64; ++kk) {
    const int cur = kk & 1;
    // Barrier: (a) drains vmcnt -> buf[cur] resident (loads issued one full
    // iteration ago); (b) all waves done reading buf[cur^1].
    __syncthreads();
    if (kk < DK / 64 - 1) {
      const int nxt = cur ^ 1;
      async_ld16(gA0, &As[nxt][lds0]);
      async_ld16(gA1, &As[nxt][lds1]);
      async_ld16(gB0, &Bs[nxt][lds0]);
      async_ld16(gB1, &Bs[nxt][lds1]);
      gA0 += 64; gA1 += 64; gB0 += 64; gB1 += 64;
    }

    const char* Ab = As[cur];
    const char* Bb = Bs[cur];
    long af0[4], af1[4], bf0[4], bf1[4];
#pragma unroll
    for (int mi = 0; mi < 4; ++mi) {
      longx2 t = *(const longx2*)(Ab + offA[mi]);
      af0[mi] = t.x; af1[mi] = t.y;
    }
#pragma unroll
    for (int ni = 0; ni < 4; ++ni) {
      longx2 t = *(const longx2*)(Bb + offB[ni]);
      bf0[ni] = t.x; bf1[ni] = t.y;
    }
#pragma unroll
    for (int mi = 0; mi < 4; ++mi)
#pragma unroll
      for (int ni = 0; ni < 4; ++ni)
        acc[mi][ni] = __builtin_amdgcn_mfma_f32_16x16x32_fp8_fp8(
            af0[mi], bf0[ni], acc[mi][ni], 0, 0, 0);
#pragma unroll
    for (int mi = 0; mi < 4; ++mi)
#pragma unroll
      for (int ni = 0; ni < 4; ++ni)
        acc[mi][ni] = __builtin_amdgcn_mfma_f32_16x16x32_fp8_fp8(
            af1[mi], bf1[ni], acc[mi][ni], 0, 0, 0);
  }

  // epilogue: rowsum[m] += sum_n exp(64 * wf[m][n])
  const int rowq = (lane >> 4) * 4;  // C/D layout: row = quad*4 + reg
#pragma unroll
  for (int mi = 0; mi < 4; ++mi) {
#pragma unroll
    for (int r = 0; r < 4; ++r) {
      float v = 0.f;
#pragma unroll
      for (int ni = 0; ni < 4; ++ni)
        v += __expf(64.0f * acc[mi][ni][r]);
      v += __shfl_xor(v, 1, 64);
      v += __shfl_xor(v, 2, 64);
      v += __shfl_xor(v, 4, 64);
      v += __shfl_xor(v, 8, 64);
      if ((lane & 15) == 0)
        atomicAdd(&lsum[wm + mi * 16 + rowq + r], v);
    }
  }
  __syncthreads();
  if (tid < 128)
    atomicAdd(&rowsum[tileM + tid], lsum[tid]);
}

// ---- kernel 3: final loss
__global__ void loss_kernel(const float* __restrict__ tgt,
                            const float* __restrict__ rowsum,
                            float* __restrict__ out) {
  __shared__ float wsum[8];
  const int t = threadIdx.x;
  float sum = 0.f;
  const float cM = 0.87758256189037271f;  // cos(0.5)
  const float sM = 0.47942553860420301f;  // sin(0.5)
  for (int i = t; i < BN; i += 512) {
    const float tg_raw = tgt[i];
    const float tg = fminf(fmaxf(tg_raw, -1.f + 1e-7f), 1.f - 1e-7f);
    const float num = 64.f * (tg * cM - sqrtf(fmaxf(1.f - tg * tg, 0.f)) * sM);
    const float den = expf(num) + rowsum[i] - expf(64.f * tg_raw);
    sum += num - logf(den);
  }
#pragma unroll
  for (int off = 1; off < 64; off <<= 1) sum += __shfl_xor(sum, off, 64);
  if ((t & 63) == 0) wsum[t >> 6] = sum;
  __syncthreads();
  if (t == 0) {
    float tot = 0.f;
#pragma unroll
    for (int k = 0; k < 8; ++k) tot += wsum[k];
    out[0] = -tot * (1.0f / (float)BN);
  }
}

extern "C" void kernel_launch(void* const* d_in, const int* in_sizes, int n_in,
                              void* d_out, int out_size, void* d_ws, size_t ws_size,
                              hipStream_t stream) {
  const float* features = (const float*)d_in[0];
  const int*   y_true   = (const int*)d_in[1];
  const float* weight   = (const float*)d_in[2];
  float* out = (float*)d_out;

  char* ws = (char*)d_ws;
  char* wb8    = ws;                          // 16 MB
  char* fb8    = ws + 16777216;               //  1 MB
  float* tgt    = (float*)(ws + 17825792);    //  8 KB
  float* rowsum = (float*)(ws + 17833984);    //  8 KB

  prep_kernel<<<8192 + 512, 256, 0, stream>>>(features, y_true, weight,
                                              (int*)fb8, (int*)wb8, tgt, rowsum);
  gemm_exp_kernel<<<4096, 256, 0, stream>>>(fb8, wb8, rowsum);
  loss_kernel<<<1, 512, 0, stream>>>(tgt, rowsum, out);
}